// Round 4
// baseline (54.380 us; speedup 1.0000x reference)
//
#include <hip/hip_runtime.h>
#include <hip/hip_bf16.h>

#define FEATS 512
#define NW 5
#define NH 16
#define NOUT 5

// ws (floats): [0,512) x_orig | [512,1024) x_sorted | [1024,3584) acc[o*512+i] | [3584] ticket
#define ACC_OFF 1024
#define CNT_OFF (ACC_OFF + FEATS * NOUT)
#define WS_FLOATS_NEEDED (CNT_OFF + 1)

// ---------------- Kernel A: window-sum + parallel rank sort + zero acc (64 blocks) ----
__global__ __launch_bounds__(512) void prep_sort(const float* __restrict__ data,
                                                 float* __restrict__ ws) {
    __shared__ float xs[FEATS];
    const int t = threadIdx.x;
    float v = 0.f;
    #pragma unroll
    for (int w = 0; w < NW; ++w) v += data[w * FEATS + t];
    xs[t] = v;
    __syncthreads();

    const int wid = t >> 6, lane = t & 63;
    const int i = blockIdx.x * 8 + wid;
    const float vi = xs[i];               // wave-uniform -> LDS broadcast
    int r = 0;
    #pragma unroll
    for (int u = 0; u < 8; ++u) {
        const int j = u * 64 + lane;
        const float xj = xs[j];
        r += (xj < vi) || (xj == vi && j < i);   // stable -> rank is a permutation
    }
    #pragma unroll
    for (int off = 32; off; off >>= 1) r += __shfl_xor(r, off);
    if (lane == 0) ws[FEATS + r] = vi;    // x_sorted ascending
    if (blockIdx.x == 0) ws[t] = xs[t];   // x_orig

    // zero the output accumulator + ticket counter (must happen every launch:
    // harness poisons ws once with 0xAA and never re-poisons between replays)
    const int g = blockIdx.x * 512 + t;
    if (g <= FEATS * NOUT) ws[ACC_OFF + g] = 0.f;
}

// ---------------- Kernel B: GAT heads + collapsed MLP + ticket finalize (256 blocks) --
// leaky(.,1.0)==identity => fcn is affine: out = sigmoid(feat_r @ (F2@F1)^T + F2@fb1+fb2).
// Block b handles heads {2b, 2b+1}: shfl-scan prefix tables over sorted x, binary-search
// epilogue per dst i, project onto G[:,h], pre-reduce over the 2 heads in registers,
// atomicAdd into acc. Last block (atomic ticket) applies sigmoid and writes d_out.
__global__ __launch_bounds__(512) void gat_mlp(
    float* __restrict__ ws,
    const float* __restrict__ gat_w, const float* __restrict__ a_src,
    const float* __restrict__ a_dst, const float* __restrict__ gat_bias,
    const float* __restrict__ F1, const float* __restrict__ fb1,
    const float* __restrict__ F2, const float* __restrict__ fb2,
    float* __restrict__ out)
{
    __shared__ float xsrt[FEATS];
    __shared__ float4 pre[FEATS + 1];
    __shared__ float4 wtot[8];
    __shared__ int amLast;

    const int t = threadIdx.x;
    const int lane = t & 63, wid = t >> 6;
    const float LOG2E = 1.4426950408889634f;

    const float xv = ws[FEATS + t];       // sorted x
    const float xi = ws[t];               // original x (dst term), thread t = dst i
    xsrt[t] = xv;

    float accv[NOUT] = {0.f, 0.f, 0.f, 0.f, 0.f};

    #pragma unroll
    for (int hh = 0; hh < 2; ++hh) {
        const int h = blockIdx.x * 2 + hh;
        const float gwv = gat_w[h];
        const float cs  = gwv * a_src[h] * LOG2E;
        const float cd  = gwv * a_dst[h] * LOG2E;

        const float p1 = __builtin_amdgcn_exp2f(cs * xv);
        const float p2 = __builtin_amdgcn_exp2f(0.2f * cs * xv);
        float4 s = make_float4(p1, p2, xv * p1, xv * p2);

        // 64-lane inclusive scan, register-only
        #pragma unroll
        for (int d = 1; d < 64; d <<= 1) {
            const float ax = __shfl_up(s.x, d);
            const float ay = __shfl_up(s.y, d);
            const float az = __shfl_up(s.z, d);
            const float aw = __shfl_up(s.w, d);
            if (lane >= d) { s.x += ax; s.y += ay; s.z += az; s.w += aw; }
        }
        if (lane == 63) wtot[wid] = s;
        __syncthreads();
        float4 o4 = make_float4(0.f, 0.f, 0.f, 0.f);
        #pragma unroll
        for (int w = 0; w < 7; ++w) {
            if (w < wid) {
                const float4 u = wtot[w];
                o4.x += u.x; o4.y += u.y; o4.z += u.z; o4.w += u.w;
            }
        }
        s.x += o4.x; s.y += o4.y; s.z += o4.z; s.w += o4.w;
        pre[t + 1] = s;                   // exclusive prefix: pre[k] = sum_{m<k}
        if (t == 0) pre[0] = make_float4(0.f, 0.f, 0.f, 0.f);
        __syncthreads();

        // epilogue for dst i = t
        const float dterm = cd * xi;
        const bool csn = (cs >= 0.f);
        int m = 0;
        #pragma unroll
        for (int step = 256; step; step >>= 1) {
            const int cand = m + step;
            const float tt = fmaf(xsrt[cand - 1], cs, dterm);
            const bool p = csn ? (tt >= 0.f) : (tt < 0.f);
            if (!p) m = cand;
        }
        const float4 P = pre[m];
        const float4 T = pre[FEATS];
        const float A1 = __builtin_amdgcn_exp2f(dterm);
        const float A2 = __builtin_amdgcn_exp2f(0.2f * dterm);
        float Se, Sv;
        if (csn) {
            Se = A1 * (T.x - P.x) + A2 * P.y;
            Sv = A1 * (T.z - P.z) + A2 * P.w;
        } else {
            Se = A1 * P.x + A2 * (T.y - P.y);
            Sv = A1 * P.z + A2 * (T.w - P.w);
        }
        const float fv = gwv * (Sv / Se) + gat_bias[h];

        // project onto G[:,h] = F2 @ F1[:,h]  (wave-uniform, scalarized loads)
        #pragma unroll
        for (int o = 0; o < NOUT; ++o) {
            float g = 0.f;
            #pragma unroll
            for (int k = 0; k < NH; ++k) g = fmaf(F2[o * NH + k], F1[k * FEATS + h], g);
            accv[o] = fmaf(g, fv, accv[o]);
        }
        __syncthreads();                  // protect pre/wtot reuse by next head
    }

    float* acc = ws + ACC_OFF;
    #pragma unroll
    for (int o = 0; o < NOUT; ++o)
        atomicAdd(&acc[o * FEATS + t], accv[o]);

    __threadfence();                      // drain this thread's atomics device-wide
    __syncthreads();
    if (t == 0) {
        const int old = atomicAdd((int*)(ws + CNT_OFF), 1);
        amLast = (old == (FEATS / 2) - 1);
    }
    __syncthreads();
    if (amLast) {
        __threadfence();
        float cp[NOUT];
        #pragma unroll
        for (int o = 0; o < NOUT; ++o) {
            float c = fb2[o];
            #pragma unroll
            for (int k = 0; k < NH; ++k) c = fmaf(F2[o * NH + k], fb1[k], c);
            cp[o] = c;
        }
        #pragma unroll
        for (int o = 0; o < NOUT; ++o) {
            const float sval = __hip_atomic_load(&acc[o * FEATS + t],
                                                 __ATOMIC_ACQUIRE,
                                                 __HIP_MEMORY_SCOPE_AGENT) + cp[o];
            out[t * NOUT + o] = 1.f / (1.f + __builtin_amdgcn_exp2f(-sval * LOG2E));
        }
    }
}

// ---------------- Fallback: fused O(N^3) kernel (if ws too small) ----------------
__global__ __launch_bounds__(512) void gat_fused_fb(
    const float* __restrict__ data,
    const float* __restrict__ gat_w, const float* __restrict__ a_src,
    const float* __restrict__ a_dst, const float* __restrict__ gat_bias,
    const float* __restrict__ F1, const float* __restrict__ fb1,
    const float* __restrict__ F2, const float* __restrict__ fb2,
    float* __restrict__ out)
{
    __shared__ __align__(16) float xs[FEATS];
    __shared__ float feat[FEATS];
    __shared__ float part[NH][8];
    __shared__ float hv[NH];
    const int h = threadIdx.x;
    const int i = blockIdx.x;
    float v = 0.f;
    #pragma unroll
    for (int w = 0; w < NW; ++w) v += data[w * FEATS + h];
    xs[h] = v;
    __syncthreads();
    const float LOG2E = 1.4426950408889634f;
    const float gwv = gat_w[h];
    const float cs = gwv * a_src[h] * LOG2E;
    const float cd = gwv * a_dst[h] * LOG2E;
    const float di = xs[i] * cd;
    float se = 0.f, sv = 0.f;
    const float4* x4 = (const float4*)xs;
    for (int j4 = 0; j4 < FEATS / 4; ++j4) {
        float4 q = x4[j4];
        #pragma unroll
        for (int u = 0; u < 4; ++u) {
            float xj = (u == 0) ? q.x : (u == 1) ? q.y : (u == 2) ? q.z : q.w;
            float tt = fmaf(xj, cs, di);
            float l  = fmaxf(tt, 0.2f * tt);
            float e  = __builtin_amdgcn_exp2f(l);
            se += e;
            sv = fmaf(e, xj, sv);
        }
    }
    feat[h] = gwv * sv / se + gat_bias[h];
    __syncthreads();
    const int lane = h & 63, wid = h >> 6;
    const float fv = feat[h];
    for (int k = 0; k < NH; ++k) {
        float p = fv * F1[k * FEATS + h];
        #pragma unroll
        for (int off = 32; off; off >>= 1) p += __shfl_xor(p, off);
        if (lane == 0) part[k][wid] = p;
    }
    __syncthreads();
    if (h < NH) {
        float s = fb1[h];
        #pragma unroll
        for (int w = 0; w < 8; ++w) s += part[h][w];
        hv[h] = s;
    }
    __syncthreads();
    if (h < 5) {
        float s = fb2[h];
        #pragma unroll
        for (int k = 0; k < NH; ++k) s = fmaf(hv[k], F2[h * NH + k], s);
        out[i * 5 + h] = 1.f / (1.f + __builtin_amdgcn_exp2f(-s * LOG2E));
    }
}

extern "C" void kernel_launch(void* const* d_in, const int* in_sizes, int n_in,
                              void* d_out, int out_size, void* d_ws, size_t ws_size,
                              hipStream_t stream) {
    (void)in_sizes; (void)n_in; (void)out_size;
    const float* data     = (const float*)d_in[0];
    // d_in[1..6] = W1,b1,W2,b2,W3,b3 — dead (softmax over batch dim of size 1 == 1)
    const float* gat_w    = (const float*)d_in[7];
    const float* a_src    = (const float*)d_in[8];
    const float* a_dst    = (const float*)d_in[9];
    const float* gat_bias = (const float*)d_in[10];
    const float* F1       = (const float*)d_in[11];
    const float* fb1      = (const float*)d_in[12];
    const float* F2       = (const float*)d_in[13];
    const float* fb2      = (const float*)d_in[14];
    float* out = (float*)d_out;

    if (ws_size >= (size_t)WS_FLOATS_NEEDED * sizeof(float)) {
        float* ws = (float*)d_ws;
        prep_sort<<<64, FEATS, 0, stream>>>(data, ws);
        gat_mlp<<<FEATS / 2, FEATS, 0, stream>>>(ws, gat_w, a_src, a_dst, gat_bias,
                                                 F1, fb1, F2, fb2, out);
    } else {
        gat_fused_fb<<<FEATS, FEATS, 0, stream>>>(data, gat_w, a_src, a_dst, gat_bias,
                                                  F1, fb1, F2, fb2, out);
    }
}

// Round 5
// 39.070 us; speedup vs baseline: 1.3919x; 1.3919x over previous
//
#include <hip/hip_runtime.h>
#include <hip/hip_bf16.h>

#define FEATS 512
#define NW 5
#define NH 16
#define NOUT 5
#define HPB 4                      // heads per block
#define NBLK (FEATS / HPB)         // 128 blocks

// ws (floats): [0,512) x_orig | [512,1024) x_sorted | [1024,3584) acc[o*512+i] | [3584] ticket
#define ACC_OFF 1024
#define CNT_OFF (ACC_OFF + FEATS * NOUT)
#define WS_FLOATS_NEEDED (CNT_OFF + 1)

// ---------------- Kernel A: window-sum + parallel rank sort + zero acc (64 blocks) ----
__global__ __launch_bounds__(512) void prep_sort(const float* __restrict__ data,
                                                 float* __restrict__ ws) {
    __shared__ float xs[FEATS];
    const int t = threadIdx.x;
    float v = 0.f;
    #pragma unroll
    for (int w = 0; w < NW; ++w) v += data[w * FEATS + t];
    xs[t] = v;
    __syncthreads();

    const int wid = t >> 6, lane = t & 63;
    const int i = blockIdx.x * 8 + wid;
    const float vi = xs[i];               // wave-uniform -> LDS broadcast
    int r = 0;
    #pragma unroll
    for (int u = 0; u < 8; ++u) {
        const int j = u * 64 + lane;
        const float xj = xs[j];
        r += (xj < vi) || (xj == vi && j < i);   // stable -> rank is a permutation
    }
    #pragma unroll
    for (int off = 32; off; off >>= 1) r += __shfl_xor(r, off);
    if (lane == 0) ws[FEATS + r] = vi;    // x_sorted ascending
    if (blockIdx.x == 0) ws[t] = xs[t];   // x_orig

    // zero acc + ticket every launch (harness poisons ws once with 0xAA;
    // graph replays must start from zero)
    const int g = blockIdx.x * 512 + t;
    if (g <= FEATS * NOUT) ws[ACC_OFF + g] = 0.f;
}

// ---------------- Kernel B: GAT heads + collapsed MLP + ticket finalize (128 blocks) --
// leaky(.,1.0)==identity => fcn is affine: out = sigmoid(feat_r @ (F2@F1)^T + F2@fb1+fb2).
// Block b handles 4 heads; per head: shfl-scan prefix tables over sorted x (SoA in LDS),
// binary-search epilogue per dst i, project onto G[:,h]=F2@F1[:,h], pre-reduce the 4
// heads in registers, then ONE native fp32 atomic per (o,i). Ticket-last block applies
// the sigmoid and writes d_out.
__global__ __launch_bounds__(512) void gat_mlp(
    float* __restrict__ ws,
    const float* __restrict__ gat_w, const float* __restrict__ a_src,
    const float* __restrict__ a_dst, const float* __restrict__ gat_bias,
    const float* __restrict__ F1, const float* __restrict__ fb1,
    const float* __restrict__ F2, const float* __restrict__ fb2,
    float* __restrict__ out)
{
    __shared__ float xsrt[FEATS];
    __shared__ float preX[FEATS + 1], preY[FEATS + 1], preZ[FEATS + 1], preW[FEATS + 1];
    __shared__ float4 wtot[8];
    __shared__ int amLast;

    const int t = threadIdx.x;
    const int lane = t & 63, wid = t >> 6;
    const float LOG2E = 1.4426950408889634f;

    const float xv = ws[FEATS + t];       // sorted x
    const float xi = ws[t];               // original x (dst term), thread t = dst i
    xsrt[t] = xv;

    float accv[NOUT] = {0.f, 0.f, 0.f, 0.f, 0.f};

    #pragma unroll
    for (int hh = 0; hh < HPB; ++hh) {
        const int h = blockIdx.x * HPB + hh;
        const float gwv = gat_w[h];
        const float cs  = gwv * a_src[h] * LOG2E;
        const float cd  = gwv * a_dst[h] * LOG2E;

        const float p1 = __builtin_amdgcn_exp2f(cs * xv);
        const float p2 = __builtin_amdgcn_exp2f(0.2f * cs * xv);
        float4 s = make_float4(p1, p2, xv * p1, xv * p2);

        // 64-lane inclusive scan, register-only
        #pragma unroll
        for (int d = 1; d < 64; d <<= 1) {
            const float ax = __shfl_up(s.x, d);
            const float ay = __shfl_up(s.y, d);
            const float az = __shfl_up(s.z, d);
            const float aw = __shfl_up(s.w, d);
            if (lane >= d) { s.x += ax; s.y += ay; s.z += az; s.w += aw; }
        }
        if (lane == 63) wtot[wid] = s;
        __syncthreads();
        float4 o4 = make_float4(0.f, 0.f, 0.f, 0.f);
        #pragma unroll
        for (int w = 0; w < 7; ++w) {
            if (w < wid) {
                const float4 u = wtot[w];          // wave-uniform -> broadcast
                o4.x += u.x; o4.y += u.y; o4.z += u.z; o4.w += u.w;
            }
        }
        s.x += o4.x; s.y += o4.y; s.z += o4.z; s.w += o4.w;
        // SoA exclusive prefix (stride-1 b32 writes: conflict-free)
        preX[t + 1] = s.x; preY[t + 1] = s.y; preZ[t + 1] = s.z; preW[t + 1] = s.w;
        if (t == 0) { preX[0] = 0.f; preY[0] = 0.f; preZ[0] = 0.f; preW[0] = 0.f; }
        __syncthreads();

        // epilogue for dst i = t
        const float dterm = cd * xi;
        const bool csn = (cs >= 0.f);
        int m = 0;
        #pragma unroll
        for (int step = 256; step; step >>= 1) {
            const int cand = m + step;
            const float tt = fmaf(xsrt[cand - 1], cs, dterm);
            const bool p = csn ? (tt >= 0.f) : (tt < 0.f);
            if (!p) m = cand;
        }
        const float Px = preX[m], Py = preY[m], Pz = preZ[m], Pw = preW[m];
        const float Tx = preX[FEATS], Ty = preY[FEATS], Tz = preZ[FEATS], Tw = preW[FEATS];
        const float A1 = __builtin_amdgcn_exp2f(dterm);
        const float A2 = __builtin_amdgcn_exp2f(0.2f * dterm);
        float Se, Sv;
        if (csn) {
            Se = A1 * (Tx - Px) + A2 * Py;
            Sv = A1 * (Tz - Pz) + A2 * Pw;
        } else {
            Se = A1 * Px + A2 * (Ty - Py);
            Sv = A1 * Pz + A2 * (Tw - Pw);
        }
        const float fv = gwv * (Sv / Se) + gat_bias[h];

        // project onto G[:,h] = F2 @ F1[:,h]  (h uniform per block -> scalar loads)
        #pragma unroll
        for (int o = 0; o < NOUT; ++o) {
            float g = 0.f;
            #pragma unroll
            for (int k = 0; k < NH; ++k) g = fmaf(F2[o * NH + k], F1[k * FEATS + h], g);
            accv[o] = fmaf(g, fv, accv[o]);
        }
        __syncthreads();                  // protect pre/wtot reuse by next head
    }

    float* acc = ws + ACC_OFF;
    #pragma unroll
    for (int o = 0; o < NOUT; ++o)
        unsafeAtomicAdd(&acc[o * FEATS + t], accv[o]);   // native global_atomic_add_f32

    // order: my posted atomics must complete before the ticket increment
    asm volatile("s_waitcnt vmcnt(0)" ::: "memory");
    __syncthreads();
    if (t == 0) {
        const int old = __hip_atomic_fetch_add((int*)(ws + CNT_OFF), 1,
                                               __ATOMIC_ACQ_REL,
                                               __HIP_MEMORY_SCOPE_AGENT);
        amLast = (old == NBLK - 1);
    }
    __syncthreads();
    if (amLast) {
        float cp[NOUT];
        #pragma unroll
        for (int o = 0; o < NOUT; ++o) {
            float c = fb2[o];
            #pragma unroll
            for (int k = 0; k < NH; ++k) c = fmaf(F2[o * NH + k], fb1[k], c);
            cp[o] = c;
        }
        #pragma unroll
        for (int o = 0; o < NOUT; ++o) {
            const float sval = __hip_atomic_load(&acc[o * FEATS + t],
                                                 __ATOMIC_ACQUIRE,
                                                 __HIP_MEMORY_SCOPE_AGENT) + cp[o];
            out[t * NOUT + o] = 1.f / (1.f + __builtin_amdgcn_exp2f(-sval * LOG2E));
        }
    }
}

// ---------------- Fallback: fused O(N^3) kernel (if ws too small) ----------------
__global__ __launch_bounds__(512) void gat_fused_fb(
    const float* __restrict__ data,
    const float* __restrict__ gat_w, const float* __restrict__ a_src,
    const float* __restrict__ a_dst, const float* __restrict__ gat_bias,
    const float* __restrict__ F1, const float* __restrict__ fb1,
    const float* __restrict__ F2, const float* __restrict__ fb2,
    float* __restrict__ out)
{
    __shared__ __align__(16) float xs[FEATS];
    __shared__ float feat[FEATS];
    __shared__ float part[NH][8];
    __shared__ float hv[NH];
    const int h = threadIdx.x;
    const int i = blockIdx.x;
    float v = 0.f;
    #pragma unroll
    for (int w = 0; w < NW; ++w) v += data[w * FEATS + h];
    xs[h] = v;
    __syncthreads();
    const float LOG2E = 1.4426950408889634f;
    const float gwv = gat_w[h];
    const float cs = gwv * a_src[h] * LOG2E;
    const float cd = gwv * a_dst[h] * LOG2E;
    const float di = xs[i] * cd;
    float se = 0.f, sv = 0.f;
    const float4* x4 = (const float4*)xs;
    for (int j4 = 0; j4 < FEATS / 4; ++j4) {
        float4 q = x4[j4];
        #pragma unroll
        for (int u = 0; u < 4; ++u) {
            float xj = (u == 0) ? q.x : (u == 1) ? q.y : (u == 2) ? q.z : q.w;
            float tt = fmaf(xj, cs, di);
            float l  = fmaxf(tt, 0.2f * tt);
            float e  = __builtin_amdgcn_exp2f(l);
            se += e;
            sv = fmaf(e, xj, sv);
        }
    }
    feat[h] = gwv * sv / se + gat_bias[h];
    __syncthreads();
    const int lane = h & 63, wid = h >> 6;
    const float fv = feat[h];
    for (int k = 0; k < NH; ++k) {
        float p = fv * F1[k * FEATS + h];
        #pragma unroll
        for (int off = 32; off; off >>= 1) p += __shfl_xor(p, off);
        if (lane == 0) part[k][wid] = p;
    }
    __syncthreads();
    if (h < NH) {
        float s = fb1[h];
        #pragma unroll
        for (int w = 0; w < 8; ++w) s += part[h][w];
        hv[h] = s;
    }
    __syncthreads();
    if (h < 5) {
        float s = fb2[h];
        #pragma unroll
        for (int k = 0; k < NH; ++k) s = fmaf(hv[k], F2[h * NH + k], s);
        out[i * 5 + h] = 1.f / (1.f + __builtin_amdgcn_exp2f(-s * LOG2E));
    }
}

extern "C" void kernel_launch(void* const* d_in, const int* in_sizes, int n_in,
                              void* d_out, int out_size, void* d_ws, size_t ws_size,
                              hipStream_t stream) {
    (void)in_sizes; (void)n_in; (void)out_size;
    const float* data     = (const float*)d_in[0];
    // d_in[1..6] = W1,b1,W2,b2,W3,b3 — dead (softmax over batch dim of size 1 == 1)
    const float* gat_w    = (const float*)d_in[7];
    const float* a_src    = (const float*)d_in[8];
    const float* a_dst    = (const float*)d_in[9];
    const float* gat_bias = (const float*)d_in[10];
    const float* F1       = (const float*)d_in[11];
    const float* fb1      = (const float*)d_in[12];
    const float* F2       = (const float*)d_in[13];
    const float* fb2      = (const float*)d_in[14];
    float* out = (float*)d_out;

    if (ws_size >= (size_t)WS_FLOATS_NEEDED * sizeof(float)) {
        float* ws = (float*)d_ws;
        prep_sort<<<64, FEATS, 0, stream>>>(data, ws);
        gat_mlp<<<NBLK, FEATS, 0, stream>>>(ws, gat_w, a_src, a_dst, gat_bias,
                                            F1, fb1, F2, fb2, out);
    } else {
        gat_fused_fb<<<FEATS, FEATS, 0, stream>>>(data, gat_w, a_src, a_dst, gat_bias,
                                                  F1, fb1, F2, fb2, out);
    }
}

// Round 6
// 34.572 us; speedup vs baseline: 1.5730x; 1.1301x over previous
//
#include <hip/hip_runtime.h>
#include <hip/hip_bf16.h>

#define FEATS 512
#define NW 5
#define NH 16
#define NOUT 5
#define HPB 4                      // heads per block
#define NBLK (FEATS / HPB)         // 128 blocks

// ws (floats): [0,512) x_orig | [512,1024) x_sorted | [1024,3584) acc[o*512+i] | [3584] ticket
#define ACC_OFF 1024
#define CNT_OFF (ACC_OFF + FEATS * NOUT)
#define WS_FLOATS_NEEDED (CNT_OFF + 1)

// ---------------- Kernel A: window-sum + parallel rank sort + zero acc (64 blocks) ----
__global__ __launch_bounds__(512) void prep_sort(const float* __restrict__ data,
                                                 float* __restrict__ ws) {
    __shared__ float xs[FEATS];
    const int t = threadIdx.x;
    float v = 0.f;
    #pragma unroll
    for (int w = 0; w < NW; ++w) v += data[w * FEATS + t];
    xs[t] = v;
    __syncthreads();

    const int wid = t >> 6, lane = t & 63;
    const int i = blockIdx.x * 8 + wid;
    const float vi = xs[i];               // wave-uniform -> LDS broadcast
    int r = 0;
    #pragma unroll
    for (int u = 0; u < 8; ++u) {
        const int j = u * 64 + lane;
        const float xj = xs[j];
        r += (xj < vi) || (xj == vi && j < i);   // stable -> rank is a permutation
    }
    #pragma unroll
    for (int off = 32; off; off >>= 1) r += __shfl_xor(r, off);
    if (lane == 0) ws[FEATS + r] = vi;    // x_sorted ascending
    if (blockIdx.x == 0) ws[t] = xs[t];   // x_orig

    // zero acc + ticket every launch (harness poisons ws once with 0xAA;
    // graph replays must start from zero). End-of-dispatch release makes
    // these visible to kernel B.
    const int g = blockIdx.x * 512 + t;
    if (g <= FEATS * NOUT) ws[ACC_OFF + g] = 0.f;
}

// ---------------- Kernel B: GAT heads + collapsed MLP + ticket finalize (128 blocks) --
// leaky(.,1.0)==identity => fcn is affine: out = sigmoid(feat_r @ (F2@F1)^T + F2@fb1+fb2).
// Per head: shfl-scan prefix tables over sorted x (SoA in LDS), binary-search epilogue
// per dst i, project onto G[:,h]=F2@F1[:,h], pre-reduce 4 heads in registers, then ONE
// native fp32 no-return atomic per (o,i) (executes at MALL, the device coherence point).
// Ordering: s_waitcnt vmcnt(0) completes my adds BEFORE the relaxed ticket RMW issues,
// so no L2 writeback/invalidate (buffer_wbl2/buffer_inv) is ever needed — those agent
// acq/rel cache-maintenance ops were the R5 stall.
__global__ __launch_bounds__(512) void gat_mlp(
    float* __restrict__ ws,
    const float* __restrict__ gat_w, const float* __restrict__ a_src,
    const float* __restrict__ a_dst, const float* __restrict__ gat_bias,
    const float* __restrict__ F1, const float* __restrict__ fb1,
    const float* __restrict__ F2, const float* __restrict__ fb2,
    float* __restrict__ out)
{
    __shared__ float xsrt[FEATS];
    __shared__ float preX[FEATS + 1], preY[FEATS + 1], preZ[FEATS + 1], preW[FEATS + 1];
    __shared__ float4 wtot[8];
    __shared__ int amLast;

    const int t = threadIdx.x;
    const int lane = t & 63, wid = t >> 6;
    const float LOG2E = 1.4426950408889634f;

    const float xv = ws[FEATS + t];       // sorted x
    const float xi = ws[t];               // original x (dst term), thread t = dst i
    xsrt[t] = xv;

    float accv[NOUT] = {0.f, 0.f, 0.f, 0.f, 0.f};

    #pragma unroll
    for (int hh = 0; hh < HPB; ++hh) {
        const int h = blockIdx.x * HPB + hh;
        const float gwv = gat_w[h];
        const float cs  = gwv * a_src[h] * LOG2E;
        const float cd  = gwv * a_dst[h] * LOG2E;

        const float p1 = __builtin_amdgcn_exp2f(cs * xv);
        const float p2 = __builtin_amdgcn_exp2f(0.2f * cs * xv);
        float4 s = make_float4(p1, p2, xv * p1, xv * p2);

        // 64-lane inclusive scan, register-only
        #pragma unroll
        for (int d = 1; d < 64; d <<= 1) {
            const float ax = __shfl_up(s.x, d);
            const float ay = __shfl_up(s.y, d);
            const float az = __shfl_up(s.z, d);
            const float aw = __shfl_up(s.w, d);
            if (lane >= d) { s.x += ax; s.y += ay; s.z += az; s.w += aw; }
        }
        if (lane == 63) wtot[wid] = s;
        __syncthreads();
        float4 o4 = make_float4(0.f, 0.f, 0.f, 0.f);
        #pragma unroll
        for (int w = 0; w < 7; ++w) {
            if (w < wid) {
                const float4 u = wtot[w];          // wave-uniform -> broadcast
                o4.x += u.x; o4.y += u.y; o4.z += u.z; o4.w += u.w;
            }
        }
        s.x += o4.x; s.y += o4.y; s.z += o4.z; s.w += o4.w;
        // SoA exclusive prefix (stride-1 b32 writes: conflict-free)
        preX[t + 1] = s.x; preY[t + 1] = s.y; preZ[t + 1] = s.z; preW[t + 1] = s.w;
        if (t == 0) { preX[0] = 0.f; preY[0] = 0.f; preZ[0] = 0.f; preW[0] = 0.f; }
        __syncthreads();

        // epilogue for dst i = t
        const float dterm = cd * xi;
        const bool csn = (cs >= 0.f);
        int m = 0;
        #pragma unroll
        for (int step = 256; step; step >>= 1) {
            const int cand = m + step;
            const float tt = fmaf(xsrt[cand - 1], cs, dterm);
            const bool p = csn ? (tt >= 0.f) : (tt < 0.f);
            if (!p) m = cand;
        }
        const float Px = preX[m], Py = preY[m], Pz = preZ[m], Pw = preW[m];
        const float Tx = preX[FEATS], Ty = preY[FEATS], Tz = preZ[FEATS], Tw = preW[FEATS];
        const float A1 = __builtin_amdgcn_exp2f(dterm);
        const float A2 = __builtin_amdgcn_exp2f(0.2f * dterm);
        float Se, Sv;
        if (csn) {
            Se = A1 * (Tx - Px) + A2 * Py;
            Sv = A1 * (Tz - Pz) + A2 * Pw;
        } else {
            Se = A1 * Px + A2 * (Ty - Py);
            Sv = A1 * Pz + A2 * (Tw - Pw);
        }
        const float fv = gwv * (Sv / Se) + gat_bias[h];

        // project onto G[:,h] = F2 @ F1[:,h]  (h uniform per block -> scalar loads)
        #pragma unroll
        for (int o = 0; o < NOUT; ++o) {
            float g = 0.f;
            #pragma unroll
            for (int k = 0; k < NH; ++k) g = fmaf(F2[o * NH + k], F1[k * FEATS + h], g);
            accv[o] = fmaf(g, fv, accv[o]);
        }
        __syncthreads();                  // protect pre/wtot reuse by next head
    }

    float* acc = ws + ACC_OFF;
    #pragma unroll
    for (int o = 0; o < NOUT; ++o)
        unsafeAtomicAdd(&acc[o * FEATS + t], accv[o]);   // native, no-return, at MALL

    // my adds are performed (ack'd at the coherence point) before the ticket issues
    asm volatile("s_waitcnt vmcnt(0)" ::: "memory");
    __syncthreads();
    if (t == 0) {
        const int old = __hip_atomic_fetch_add((int*)(ws + CNT_OFF), 1,
                                               __ATOMIC_RELAXED,
                                               __HIP_MEMORY_SCOPE_AGENT);
        amLast = (old == NBLK - 1);
    }
    __syncthreads();   // also a compiler memory barrier: acc loads can't hoist above
    if (amLast) {
        float cp[NOUT];
        #pragma unroll
        for (int o = 0; o < NOUT; ++o) {
            float c = fb2[o];
            #pragma unroll
            for (int k = 0; k < NH; ++k) c = fmaf(F2[o * NH + k], fb1[k], c);
            cp[o] = c;
        }
        // relaxed agent loads: plain global_load (sc1), no buffer_inv. This block
        // never normal-loaded acc (atomics don't allocate in L1/L2), so no stale copies.
        #pragma unroll
        for (int o = 0; o < NOUT; ++o) {
            const float sval = __hip_atomic_load(&acc[o * FEATS + t],
                                                 __ATOMIC_RELAXED,
                                                 __HIP_MEMORY_SCOPE_AGENT) + cp[o];
            out[t * NOUT + o] = 1.f / (1.f + __builtin_amdgcn_exp2f(-sval * LOG2E));
        }
    }
}

// ---------------- Fallback: fused O(N^3) kernel (if ws too small) ----------------
__global__ __launch_bounds__(512) void gat_fused_fb(
    const float* __restrict__ data,
    const float* __restrict__ gat_w, const float* __restrict__ a_src,
    const float* __restrict__ a_dst, const float* __restrict__ gat_bias,
    const float* __restrict__ F1, const float* __restrict__ fb1,
    const float* __restrict__ F2, const float* __restrict__ fb2,
    float* __restrict__ out)
{
    __shared__ __align__(16) float xs[FEATS];
    __shared__ float feat[FEATS];
    __shared__ float part[NH][8];
    __shared__ float hv[NH];
    const int h = threadIdx.x;
    const int i = blockIdx.x;
    float v = 0.f;
    #pragma unroll
    for (int w = 0; w < NW; ++w) v += data[w * FEATS + h];
    xs[h] = v;
    __syncthreads();
    const float LOG2E = 1.4426950408889634f;
    const float gwv = gat_w[h];
    const float cs = gwv * a_src[h] * LOG2E;
    const float cd = gwv * a_dst[h] * LOG2E;
    const float di = xs[i] * cd;
    float se = 0.f, sv = 0.f;
    const float4* x4 = (const float4*)xs;
    for (int j4 = 0; j4 < FEATS / 4; ++j4) {
        float4 q = x4[j4];
        #pragma unroll
        for (int u = 0; u < 4; ++u) {
            float xj = (u == 0) ? q.x : (u == 1) ? q.y : (u == 2) ? q.z : q.w;
            float tt = fmaf(xj, cs, di);
            float l  = fmaxf(tt, 0.2f * tt);
            float e  = __builtin_amdgcn_exp2f(l);
            se += e;
            sv = fmaf(e, xj, sv);
        }
    }
    feat[h] = gwv * sv / se + gat_bias[h];
    __syncthreads();
    const int lane = h & 63, wid = h >> 6;
    const float fv = feat[h];
    for (int k = 0; k < NH; ++k) {
        float p = fv * F1[k * FEATS + h];
        #pragma unroll
        for (int off = 32; off; off >>= 1) p += __shfl_xor(p, off);
        if (lane == 0) part[k][wid] = p;
    }
    __syncthreads();
    if (h < NH) {
        float s = fb1[h];
        #pragma unroll
        for (int w = 0; w < 8; ++w) s += part[h][w];
        hv[h] = s;
    }
    __syncthreads();
    if (h < 5) {
        float s = fb2[h];
        #pragma unroll
        for (int k = 0; k < NH; ++k) s = fmaf(hv[k], F2[h * NH + k], s);
        out[i * 5 + h] = 1.f / (1.f + __builtin_amdgcn_exp2f(-s * LOG2E));
    }
}

extern "C" void kernel_launch(void* const* d_in, const int* in_sizes, int n_in,
                              void* d_out, int out_size, void* d_ws, size_t ws_size,
                              hipStream_t stream) {
    (void)in_sizes; (void)n_in; (void)out_size;
    const float* data     = (const float*)d_in[0];
    // d_in[1..6] = W1,b1,W2,b2,W3,b3 — dead (softmax over batch dim of size 1 == 1)
    const float* gat_w    = (const float*)d_in[7];
    const float* a_src    = (const float*)d_in[8];
    const float* a_dst    = (const float*)d_in[9];
    const float* gat_bias = (const float*)d_in[10];
    const float* F1       = (const float*)d_in[11];
    const float* fb1      = (const float*)d_in[12];
    const float* F2       = (const float*)d_in[13];
    const float* fb2      = (const float*)d_in[14];
    float* out = (float*)d_out;

    if (ws_size >= (size_t)WS_FLOATS_NEEDED * sizeof(float)) {
        float* ws = (float*)d_ws;
        prep_sort<<<64, FEATS, 0, stream>>>(data, ws);
        gat_mlp<<<NBLK, FEATS, 0, stream>>>(ws, gat_w, a_src, a_dst, gat_bias,
                                            F1, fb1, F2, fb2, out);
    } else {
        gat_fused_fb<<<FEATS, FEATS, 0, stream>>>(data, gat_w, a_src, a_dst, gat_bias,
                                                  F1, fb1, F2, fb2, out);
    }
}